// Round 8
// baseline (157.622 us; speedup 1.0000x reference)
//
#include <hip/hip_runtime.h>
#include <math.h>

#define G   50
#define T   24
#define B   128
#define NLP (B * T)
#define SZ  (B * G * T)   // 153600 elements per (B,G,T) output

// d_out layout (floats, concatenated in return order):
//   [0,      SZ)        P_DA   (B,G,T)
//   [SZ,     2SZ)       R_up
//   [2SZ,    3SZ)       R_dn
//   [3SZ,    3SZ+B)     obj    (B,)
//   [3SZ+B,  4SZ+B)     Cost_DA

// DPP helper (cold paths): row_ror rotate within 16-lane rows.
template <int CTRL>
__device__ __forceinline__ float dpp_mov(float x) {
    int r = __builtin_amdgcn_update_dpp(0, __float_as_int(x), CTRL, 0xf, 0xf, true);
    return __int_as_float(r);
}

__device__ __forceinline__ float row_sum1(float a) {
    a += dpp_mov<0x121>(a);
    a += dpp_mov<0x122>(a);
    a += dpp_mov<0x124>(a);
    a += dpp_mov<0x128>(a);
    return a;
}

// All-reduce 3 values within each 16-lane ROW — fused v_add_f32_dpp, 12
// instructions, chains interleaved so each register has >=2 intervening
// instructions between write and DPP read (2-wait-state hazard). s_nop 1
// guards against the compiler-emitted producer immediately preceding.
// (R0-proven monolithic form. R3: staging buys nothing. R4: pk-forcing
// hurts. R6: rotation adds math. R7: launch-bounds is a no-op.)
__device__ __forceinline__ void row_sum3(float& a, float& b, float& c) {
    asm("s_nop 1\n\t"
        "v_add_f32_dpp %0, %0, %0 row_ror:1 row_mask:0xf bank_mask:0xf\n\t"
        "v_add_f32_dpp %1, %1, %1 row_ror:1 row_mask:0xf bank_mask:0xf\n\t"
        "v_add_f32_dpp %2, %2, %2 row_ror:1 row_mask:0xf bank_mask:0xf\n\t"
        "v_add_f32_dpp %0, %0, %0 row_ror:2 row_mask:0xf bank_mask:0xf\n\t"
        "v_add_f32_dpp %1, %1, %1 row_ror:2 row_mask:0xf bank_mask:0xf\n\t"
        "v_add_f32_dpp %2, %2, %2 row_ror:2 row_mask:0xf bank_mask:0xf\n\t"
        "v_add_f32_dpp %0, %0, %0 row_ror:4 row_mask:0xf bank_mask:0xf\n\t"
        "v_add_f32_dpp %1, %1, %1 row_ror:4 row_mask:0xf bank_mask:0xf\n\t"
        "v_add_f32_dpp %2, %2, %2 row_ror:4 row_mask:0xf bank_mask:0xf\n\t"
        "v_add_f32_dpp %0, %0, %0 row_ror:8 row_mask:0xf bank_mask:0xf\n\t"
        "v_add_f32_dpp %1, %1, %1 row_ror:8 row_mask:0xf bank_mask:0xf\n\t"
        "v_add_f32_dpp %2, %2, %2 row_ror:8 row_mask:0xf bank_mask:0xf"
        : "+v"(a), "+v"(b), "+v"(c));
}

// One wave per block; row r = lane>>4 (16 lanes) solves LP (4*blockIdx + r).
// Each lane owns 4 generator slots {lh, lh+16, lh+32, lh+48}; slot 3 valid
// iff lh<2 (50 gens). Sentinel BIG clamps invalid slots' primals to 0.
//
// This is R0's exact (non-rotated) iteration math, expressed in scalars
// (kills the v2f z0/zru/zrd broadcast movs and reg-pair churn) with the
// e/h factoring in the z-update (shared by {z1,z3}/{z2,z4}, -2 ops/slot).
__global__ __launch_bounds__(64)
void pdhg_lp_kernel(const float* __restrict__ forecast,
                    const float* __restrict__ pmin,
                    const float* __restrict__ pmax,
                    const float* __restrict__ bcost,
                    const float* __restrict__ ccost,
                    const int*   __restrict__ n_iters_p,
                    float* __restrict__ out,
                    float* __restrict__ ws_partial,   // NLP floats (or null)
                    float tau)
{
    const int lane = threadIdx.x;         // 0..63
    const int lh   = lane & 15;           // lane within row
    const int row  = lane >> 4;           // LP slot within wave
    const int lp   = blockIdx.x * 4 + row;
    const int b    = lp / T;
    const int t    = lp - b * T;
    const int n_iters = n_iters_p[0];

    const bool v3 = (lh < 2);             // slot 3 (gen lh+48) valid?

    float bj[4], cj[4], pmx[4], pmn[4];
    #pragma unroll
    for (int k = 0; k < 3; ++k) {
        const int g = lh + 16 * k;
        bj[k] = bcost[g]; cj[k] = ccost[g]; pmx[k] = pmax[g]; pmn[k] = pmin[g];
    }
    {
        const int g = lh + 48;
        bj[3]  = v3 ? bcost[g] : 0.f;
        cj[3]  = v3 ? ccost[g] : 0.f;
        pmx[3] = v3 ? pmax[g]  : 0.f;
        pmn[3] = v3 ? pmin[g]  : 0.f;
    }
    const float f = forecast[lp];         // uniform within each row

    const float ts  = tau * tau;          // sigma == tau
    const float nts = -ts;
    const float BIG = 1e30f;              // sentinel

    float tcP[4], tcRu[4], tcRd[4], ntspmx[4], tspmn[4];
    #pragma unroll
    for (int k = 0; k < 4; ++k) {
        tcP[k]    = tau * bj[k];
        tcRu[k]   = tau * 0.05f * bj[k];
        tcRd[k]   = tau * 0.02f * bj[k];
        ntspmx[k] = nts * pmx[k];
        tspmn[k]  = ts  * pmn[k];
    }
    if (!v3) { tcP[3] = BIG; tcRu[3] = BIG; tcRd[3] = BIG; }

    const float tsf   = ts * f;
    const float tsreq = ts * 0.02f * f;   // REQ_UP_RATIO == REQ_DN_RATIO

    float P[4], Ru[4], Rd[4], z1[4], z2[4], z3[4], z4[4];
    #pragma unroll
    for (int k = 0; k < 4; ++k) {
        P[k] = Ru[k] = Rd[k] = 0.f;
        z1[k] = z2[k] = z3[k] = z4[k] = 0.f;
    }
    float z0 = 0.f, zru = 0.f, zrd = 0.f; // row-uniform scaled duals

    for (int it = 0; it < n_iters; ++it) {
        // ---- x-update: x_new = max(x - tau*c - K^T z, 0) + overrelax ----
        float Pb[4], Rub[4], Rdb[4];
        #pragma unroll
        for (int k = 0; k < 4; ++k) {
            const float gP  = (z1[k] - z2[k]) + (z3[k] - z4[k]) + z0;
            const float Pn  = fmaxf(P[k]  - tcP[k]  - gP,           0.f);
            const float Run = fmaxf(Ru[k] - tcRu[k] - (z1[k] - zru), 0.f);
            const float Rdn = fmaxf(Rd[k] - tcRd[k] - (z2[k] - zrd), 0.f);
            Pb[k]  = __builtin_fmaf(2.f, Pn,  -P[k]);
            Rub[k] = __builtin_fmaf(2.f, Run, -Ru[k]);
            Rdb[k] = __builtin_fmaf(2.f, Rdn, -Rd[k]);
            P[k] = Pn; Ru[k] = Run; Rd[k] = Rdn;
        }

        // ---- row sums of x_bar (tree within lane, then DPP across row) ----
        float sP  = (Pb[0]  + Pb[1])  + (Pb[2]  + Pb[3]);
        float sRu = (Rub[0] + Rub[1]) + (Rub[2] + Rub[3]);
        float sRd = (Rdb[0] + Rdb[1]) + (Rdb[2] + Rdb[3]);
        row_sum3(sP, sRu, sRd);

        // ---- z-update: z += ts*(K x_bar - q), clamp ineq rows ----
        // e = ts*Pb - ts*pmax (shared z1/z3); h = ts*pmin - ts*Pb (z2/z4)
        #pragma unroll
        for (int k = 0; k < 4; ++k) {
            const float e = __builtin_fmaf(ts,  Pb[k], ntspmx[k]);
            const float h = __builtin_fmaf(nts, Pb[k], tspmn[k]);
            z3[k] = fmaxf(z3[k] + e, 0.f);                             // P <= pmax
            z4[k] = fmaxf(z4[k] + h, 0.f);                             // -P <= -pmin
            z1[k] = fmaxf(z1[k] + __builtin_fmaf(ts, Rub[k], e), 0.f); // P+Ru <= pmax
            z2[k] = fmaxf(z2[k] + __builtin_fmaf(ts, Rdb[k], h), 0.f); // -P+Rd <= -pmin
        }

        // ---- row-uniform scalar duals ----
        z0  = __builtin_fmaf(ts, sP, z0) - tsf;                    // equality
        zru = fmaxf(__builtin_fmaf(nts, sRu, zru + tsreq), 0.f);   // -sum Ru <= -req
        zrd = fmaxf(__builtin_fmaf(nts, sRd, zrd + tsreq), 0.f);   // -sum Rd <= -req
    }

    {
        const int bgt = b * (G * T) + t;
        #pragma unroll
        for (int k = 0; k < 4; ++k) {
            if (k < 3 || v3) {
                const float cost = __builtin_fmaf(bj[k], P[k], cj[k]);
                const int a = bgt + (lh + 16 * k) * T;
                out[a] = P[k];  out[SZ + a] = Ru[k];  out[2*SZ + a] = Rd[k];
                out[3*SZ + B + a] = cost;
            }
        }
    }

    if (ws_partial) {
        // per-(b,t) objective partial: sum_g cost + 0.05*b*Ru + 0.02*b*Rd
        float lo = 0.f;
        #pragma unroll
        for (int k = 0; k < 4; ++k) {
            const float cost = __builtin_fmaf(bj[k], P[k], cj[k]);
            lo += cost + 0.05f * bj[k] * Ru[k] + 0.02f * bj[k] * Rd[k];
        }
        float tot = row_sum1(lo);
        if (lh == 0) ws_partial[lp] = tot;
    }
}

// obj[b] = sum_t ws_partial[b*T + t]   (deterministic, tiny)
__global__ __launch_bounds__(64)
void obj_final_kernel(const float* __restrict__ ws_partial, float* __restrict__ out)
{
    const int b = blockIdx.x * 64 + threadIdx.x;
    if (b < B) {
        float s = 0.f;
        #pragma unroll
        for (int t = 0; t < T; ++t) s += ws_partial[b * T + t];
        out[3 * SZ + b] = s;
    }
}

// Fallback (ws too small): recompute obj from outputs, one block per b
__global__ __launch_bounds__(256)
void obj_kernel(const float* __restrict__ bcost, float* __restrict__ out)
{
    const int b = blockIdx.x;
    const float* Ru = out + SZ     + (size_t)b * (G * T);
    const float* Rd = out + 2 * SZ + (size_t)b * (G * T);
    const float* C  = out + 3 * SZ + B + (size_t)b * (G * T);

    float s = 0.f;
    for (int i = threadIdx.x; i < G * T; i += 256) {
        const int g = i / T;
        const float bg = bcost[g];
        s += C[i] + 0.05f * bg * Ru[i] + 0.02f * bg * Rd[i];
    }
    __shared__ float sm[16];
    s = row_sum1(s);                                 // 16-lane row sums
    if ((threadIdx.x & 15) == 0) sm[threadIdx.x >> 4] = s;
    __syncthreads();
    if (threadIdx.x == 0) {
        float tot = 0.f;
        #pragma unroll
        for (int i = 0; i < 16; ++i) tot += sm[i];
        out[3 * SZ + b] = tot;
    }
}

extern "C" void kernel_launch(void* const* d_in, const int* in_sizes, int n_in,
                              void* d_out, int out_size, void* d_ws, size_t ws_size,
                              hipStream_t stream) {
    const float* forecast = (const float*)d_in[0];
    const float* pmin_p   = (const float*)d_in[1];
    const float* pmax_p   = (const float*)d_in[2];
    const float* b_p      = (const float*)d_in[3];
    const float* c_p      = (const float*)d_in[4];
    const int*   niter_p  = (const int*)  d_in[5];
    float* out = (float*)d_out;

    // ||K||_2 analytic for this fixed 0/±1 structure (G=50):
    // K^T K = [[4I+J, I, -I],[I, I+J, 0],[-I, 0, I+J]]; largest eig on the
    // ones-subspace is (105+sqrt(17))/2  ->  L = sqrt((105+sqrt(17))/2)
    const double L = sqrt((105.0 + sqrt(17.0)) * 0.5);
    const float tau = (float)(0.9 / L);   // sigma == tau

    const bool use_ws = (ws_size >= (size_t)NLP * sizeof(float));
    float* wsp = use_ws ? (float*)d_ws : nullptr;

    // 16 lanes/LP, 4 LPs/wave — the proven-optimal layout (R0). Scalar
    // non-rotated body with e/h factoring: same math, fewer instructions.
    pdhg_lp_kernel<<<NLP / 4, 64, 0, stream>>>(forecast, pmin_p, pmax_p,
                                               b_p, c_p, niter_p, out, wsp, tau);
    if (use_ws) {
        obj_final_kernel<<<(B + 63) / 64, 64, 0, stream>>>(wsp, out);
    } else {
        obj_kernel<<<B, 256, 0, stream>>>(b_p, out);
    }
}

// Round 9
// 135.533 us; speedup vs baseline: 1.1630x; 1.1630x over previous
//
#include <hip/hip_runtime.h>
#include <math.h>

#define G   50
#define T   24
#define B   128
#define NLP (B * T)
#define SZ  (B * G * T)   // 153600 elements per (B,G,T) output

typedef float v2f __attribute__((ext_vector_type(2)));

// d_out layout (floats, concatenated in return order):
//   [0,      SZ)        P_DA   (B,G,T)
//   [SZ,     2SZ)       R_up
//   [2SZ,    3SZ)       R_dn
//   [3SZ,    3SZ+B)     obj    (B,)
//   [3SZ+B,  4SZ+B)     Cost_DA

__device__ __forceinline__ v2f vmax0(v2f v) {
    v2f z = {0.f, 0.f};
    return __builtin_elementwise_max(v, z);
}

// DPP helper (outside the hot loop): row_ror rotate within 16-lane rows.
template <int CTRL>
__device__ __forceinline__ float dpp_mov(float x) {
    int r = __builtin_amdgcn_update_dpp(0, __float_as_int(x), CTRL, 0xf, 0xf, true);
    return __int_as_float(r);
}

// All-reduce 3 values within each 16-lane ROW — guaranteed single-instruction
// fused v_add_f32_dpp, 12 instructions total, chains interleaved so each
// register has >=2 intervening instructions between write and DPP read
// (2-wait-state hazard). s_nop 1 guards against the compiler-emitted producer
// immediately preceding the block.
__device__ __forceinline__ void row_sum3(float& a, float& b, float& c) {
    asm("s_nop 1\n\t"
        "v_add_f32_dpp %0, %0, %0 row_ror:1 row_mask:0xf bank_mask:0xf\n\t"
        "v_add_f32_dpp %1, %1, %1 row_ror:1 row_mask:0xf bank_mask:0xf\n\t"
        "v_add_f32_dpp %2, %2, %2 row_ror:1 row_mask:0xf bank_mask:0xf\n\t"
        "v_add_f32_dpp %0, %0, %0 row_ror:2 row_mask:0xf bank_mask:0xf\n\t"
        "v_add_f32_dpp %1, %1, %1 row_ror:2 row_mask:0xf bank_mask:0xf\n\t"
        "v_add_f32_dpp %2, %2, %2 row_ror:2 row_mask:0xf bank_mask:0xf\n\t"
        "v_add_f32_dpp %0, %0, %0 row_ror:4 row_mask:0xf bank_mask:0xf\n\t"
        "v_add_f32_dpp %1, %1, %1 row_ror:4 row_mask:0xf bank_mask:0xf\n\t"
        "v_add_f32_dpp %2, %2, %2 row_ror:4 row_mask:0xf bank_mask:0xf\n\t"
        "v_add_f32_dpp %0, %0, %0 row_ror:8 row_mask:0xf bank_mask:0xf\n\t"
        "v_add_f32_dpp %1, %1, %1 row_ror:8 row_mask:0xf bank_mask:0xf\n\t"
        "v_add_f32_dpp %2, %2, %2 row_ror:8 row_mask:0xf bank_mask:0xf"
        : "+v"(a), "+v"(b), "+v"(c));
}

__device__ __forceinline__ float row_sum1(float a) {
    a += dpp_mov<0x121>(a);
    a += dpp_mov<0x122>(a);
    a += dpp_mov<0x124>(a);
    a += dpp_mov<0x128>(a);
    return a;
}

// One wave per block; row r = lane>>4 (16 lanes) solves LP (4*blockIdx + r).
// Each lane owns generators {lh, lh+16} (v2f A) and {lh+32, lh+48} (v2f B;
// B.y valid iff lh<2). 50 gens total, sentinel cost clamps invalid slots.
__global__ __launch_bounds__(64)
void pdhg_lp_kernel(const float* __restrict__ forecast,
                    const float* __restrict__ pmin,
                    const float* __restrict__ pmax,
                    const float* __restrict__ bcost,
                    const float* __restrict__ ccost,
                    const int*   __restrict__ n_iters_p,
                    float* __restrict__ out,
                    float* __restrict__ ws_partial,   // NLP floats (or null)
                    float tau)
{
    const int lane = threadIdx.x;         // 0..63
    const int lh   = lane & 15;           // lane within row
    const int row  = lane >> 4;           // LP slot within wave
    const int lp   = blockIdx.x * 4 + row;
    const int b    = lp / T;
    const int t    = lp - b * T;
    const int n_iters = n_iters_p[0];

    const int  gA0 = lh,      gA1 = lh + 16;   // always < 50
    const int  gB0 = lh + 32;                  // always < 50
    const int  gB1 = lh + 48;                  // valid iff lh < 2
    const bool vB1 = (lh < 2);

    v2f bjA  = { bcost[gA0], bcost[gA1] };
    v2f bjB  = { bcost[gB0], vB1 ? bcost[gB1] : 0.f };
    v2f cjA  = { ccost[gA0], ccost[gA1] };
    v2f cjB  = { ccost[gB0], vB1 ? ccost[gB1] : 0.f };
    v2f pmxA = { pmax[gA0],  pmax[gA1] };
    v2f pmxB = { pmax[gB0],  vB1 ? pmax[gB1] : 0.f };
    v2f pmnA = { pmin[gA0],  pmin[gA1] };
    v2f pmnB = { pmin[gB0],  vB1 ? pmin[gB1] : 0.f };
    const float f = forecast[lp];         // uniform within each row

    const float ts  = tau * tau;          // sigma == tau
    const float BIG = 1e30f;              // sentinel: clamps invalid slot to 0

    v2f tcPA  = tau * bjA;
    v2f tcPB  = tau * bjB;           if (!vB1) tcPB.y  = BIG;
    v2f tcRuA = (tau * 0.05f) * bjA;
    v2f tcRuB = (tau * 0.05f) * bjB; if (!vB1) tcRuB.y = BIG;
    v2f tcRdA = (tau * 0.02f) * bjA;
    v2f tcRdB = (tau * 0.02f) * bjB; if (!vB1) tcRdB.y = BIG;
    v2f tspmxA = ts * pmxA, tspmxB = ts * pmxB;
    v2f tspmnA = ts * pmnA, tspmnB = ts * pmnB;
    const float tsf   = ts * f;
    const float tsreq = ts * 0.02f * f;   // REQ_UP_RATIO == REQ_DN_RATIO

    v2f PA = {0,0}, PB = {0,0}, RuA = {0,0}, RuB = {0,0}, RdA = {0,0}, RdB = {0,0};
    v2f z1A = {0,0}, z1B = {0,0}, z2A = {0,0}, z2B = {0,0};
    v2f z3A = {0,0}, z3B = {0,0}, z4A = {0,0}, z4B = {0,0};   // scaled duals tau*y
    float z0 = 0.f, zru = 0.f, zrd = 0.f;                     // row-uniform

    for (int it = 0; it < n_iters; ++it) {
        // ---- x-update: x_new = max(x - (tau*c + tau*K^T y), 0) ----
        v2f z0v = { z0, z0 };
        v2f zruv = { zru, zru };
        v2f zrdv = { zrd, zrd };
        v2f gPA = (z1A - z2A) + (z3A - z4A) + z0v;
        v2f gPB = (z1B - z2B) + (z3B - z4B) + z0v;
        v2f PnA = vmax0(PA - tcPA - gPA);
        v2f PnB = vmax0(PB - tcPB - gPB);
        v2f RunA = vmax0(RuA - tcRuA - z1A + zruv);
        v2f RunB = vmax0(RuB - tcRuB - z1B + zruv);
        v2f RdnA = vmax0(RdA - tcRdA - z2A + zrdv);
        v2f RdnB = vmax0(RdB - tcRdB - z2B + zrdv);

        // overrelaxation: x_bar = 2*x_new - x_old
        v2f PbA  = 2.f * PnA  - PA,  PbB  = 2.f * PnB  - PB;
        v2f RubA = 2.f * RunA - RuA, RubB = 2.f * RunB - RuB;
        v2f RdbA = 2.f * RdnA - RdA, RdbB = 2.f * RdnB - RdB;
        PA = PnA; PB = PnB; RuA = RunA; RuB = RunB; RdA = RdnA; RdB = RdnB;

        // ---- row-local sums over generators (fused DPP adds, no LDS) ----
        v2f tP = PbA + PbB, tRu = RubA + RubB, tRd = RdbA + RdbB;
        float sP  = tP.x  + tP.y;
        float sRu = tRu.x + tRu.y;
        float sRd = tRd.x + tRd.y;
        row_sum3(sP, sRu, sRd);

        // ---- z-update: z += tau*sigma*(K x_bar - q), clamp ineq rows ----
        z0  = z0 + ts * sP - tsf;                             // equality row
        z1A = vmax0(z1A + ts * (PbA + RubA) - tspmxA);        // P+Ru <= pmax
        z1B = vmax0(z1B + ts * (PbB + RubB) - tspmxB);
        z2A = vmax0(z2A + ts * (RdbA - PbA) + tspmnA);        // -P+Rd <= -pmin
        z2B = vmax0(z2B + ts * (RdbB - PbB) + tspmnB);
        z3A = vmax0(z3A + ts * PbA - tspmxA);                 // P <= pmax
        z3B = vmax0(z3B + ts * PbB - tspmxB);
        z4A = vmax0(z4A - ts * PbA + tspmnA);                 // -P <= -pmin
        z4B = vmax0(z4B - ts * PbB + tspmnB);
        zru = fmaxf(zru + tsreq - ts * sRu, 0.f);             // -sum Ru <= -req
        zrd = fmaxf(zrd + tsreq - ts * sRd, 0.f);             // -sum Rd <= -req
    }

    const v2f costA = bjA * PA + cjA;
    const v2f costB = bjB * PB + cjB;
    {
        const int bgt = b * (G * T) + t;
        const int a0 = bgt + gA0 * T, a1 = bgt + gA1 * T, b0 = bgt + gB0 * T;
        out[a0] = PA.x;  out[SZ + a0] = RuA.x;  out[2*SZ + a0] = RdA.x;  out[3*SZ + B + a0] = costA.x;
        out[a1] = PA.y;  out[SZ + a1] = RuA.y;  out[2*SZ + a1] = RdA.y;  out[3*SZ + B + a1] = costA.y;
        out[b0] = PB.x;  out[SZ + b0] = RuB.x;  out[2*SZ + b0] = RdB.x;  out[3*SZ + B + b0] = costB.x;
        if (vB1) {
            const int b1 = bgt + gB1 * T;
            out[b1] = PB.y;  out[SZ + b1] = RuB.y;  out[2*SZ + b1] = RdB.y;  out[3*SZ + B + b1] = costB.y;
        }
    }

    if (ws_partial) {
        // per-(b,t) objective partial: sum_g cost + 0.05*b*Ru + 0.02*b*Rd
        v2f lo = costA + (0.05f * bjA) * RuA + (0.02f * bjA) * RdA
               + costB + (0.05f * bjB) * RuB + (0.02f * bjB) * RdB;
        float tot = row_sum1(lo.x + lo.y);
        if (lh == 0) ws_partial[lp] = tot;
    }
}

// obj[b] = sum_t ws_partial[b*T + t]   (deterministic, tiny)
__global__ __launch_bounds__(64)
void obj_final_kernel(const float* __restrict__ ws_partial, float* __restrict__ out)
{
    const int b = blockIdx.x * 64 + threadIdx.x;
    if (b < B) {
        float s = 0.f;
        #pragma unroll
        for (int t = 0; t < T; ++t) s += ws_partial[b * T + t];
        out[3 * SZ + b] = s;
    }
}

// Fallback (ws too small): recompute obj from outputs, one block per b
__global__ __launch_bounds__(256)
void obj_kernel(const float* __restrict__ bcost, float* __restrict__ out)
{
    const int b = blockIdx.x;
    const float* Ru = out + SZ     + (size_t)b * (G * T);
    const float* Rd = out + 2 * SZ + (size_t)b * (G * T);
    const float* C  = out + 3 * SZ + B + (size_t)b * (G * T);

    float s = 0.f;
    for (int i = threadIdx.x; i < G * T; i += 256) {
        const int g = i / T;
        const float bg = bcost[g];
        s += C[i] + 0.05f * bg * Ru[i] + 0.02f * bg * Rd[i];
    }
    __shared__ float sm[16];
    s = row_sum1(s);                                 // 16-lane row sums
    if ((threadIdx.x & 15) == 0) sm[threadIdx.x >> 4] = s;
    __syncthreads();
    if (threadIdx.x == 0) {
        float tot = 0.f;
        #pragma unroll
        for (int i = 0; i < 16; ++i) tot += sm[i];
        out[3 * SZ + b] = tot;
    }
}

extern "C" void kernel_launch(void* const* d_in, const int* in_sizes, int n_in,
                              void* d_out, int out_size, void* d_ws, size_t ws_size,
                              hipStream_t stream) {
    const float* forecast = (const float*)d_in[0];
    const float* pmin_p   = (const float*)d_in[1];
    const float* pmax_p   = (const float*)d_in[2];
    const float* b_p      = (const float*)d_in[3];
    const float* c_p      = (const float*)d_in[4];
    const int*   niter_p  = (const int*)  d_in[5];
    float* out = (float*)d_out;

    // ||K||_2 analytic for this fixed 0/±1 structure (G=50):
    // K^T K = [[4I+J, I, -I],[I, I+J, 0],[-I, 0, I+J]]; largest eig on the
    // ones-subspace is (105+sqrt(17))/2  ->  L = sqrt((105+sqrt(17))/2)
    const double L = sqrt((105.0 + sqrt(17.0)) * 0.5);
    const float tau = (float)(0.9 / L);   // sigma == tau

    const bool use_ws = (ws_size >= (size_t)NLP * sizeof(float));
    float* wsp = use_ws ? (float*)d_ws : nullptr;

    pdhg_lp_kernel<<<NLP / 4, 64, 0, stream>>>(forecast, pmin_p, pmax_p,
                                               b_p, c_p, niter_p, out, wsp, tau);
    if (use_ws) {
        obj_final_kernel<<<(B + 63) / 64, 64, 0, stream>>>(wsp, out);
    } else {
        obj_kernel<<<B, 256, 0, stream>>>(b_p, out);
    }
}